// Round 5
// baseline (7020.964 us; speedup 1.0000x reference)
//
#include <hip/hip_runtime.h>
#include <hip/hip_bf16.h>
#include <math.h>

// MoE top-2, T=8192 tokens, D=1024, F=4096, E=8.
// Inputs fp32. OUTPUT fp32 (reference returns float32; round-5 theory: the
// R3/R4 bit-identical absmax 2.875 was bf16 written into an fp32 buffer —
// position-scrambled readback). bf16 is used internally (MFMA + h/y buffers);
// tolerance is the bf16 floor (2% of ref absmax).
//
// ws (~64.3 MiB): tok_e | tok_w | tok_list | wt_list | slot_pos |
//                 cnt/off/pos | y[16384*1024]bf16 | h[4096*4096]bf16

#define D_DIM 1024
#define F_DIM 4096
#define E_NUM 8
#define T_NUM 8192
#define MAX_ROWS 4096

typedef __bf16 bf16x8_t __attribute__((ext_vector_type(8)));
typedef __bf16 bf16x4_t __attribute__((ext_vector_type(4)));
typedef float f32x4_t __attribute__((ext_vector_type(4)));
using bf16 = __hip_bfloat16;

__device__ __forceinline__ bf16x8_t cvt8(const float* __restrict__ p) {
    float4 f0 = *(const float4*)(p);
    float4 f1 = *(const float4*)(p + 4);
    bf16x8_t r;
    r[0] = (__bf16)f0.x; r[1] = (__bf16)f0.y; r[2] = (__bf16)f0.z; r[3] = (__bf16)f0.w;
    r[4] = (__bf16)f1.x; r[5] = (__bf16)f1.y; r[6] = (__bf16)f1.z; r[7] = (__bf16)f1.w;
    return r;
}

// ---------------- router: fp64-accum scores, top-2, softmax, counts ----------
__global__ __launch_bounds__(64) void moe_router(
    const float* __restrict__ x, const float* __restrict__ rw,
    int* __restrict__ cnt, int* __restrict__ tok_e, float* __restrict__ tok_w)
{
    const int t = blockIdx.x;
    const int lane = threadIdx.x;
    float xv[16];
#pragma unroll
    for (int j = 0; j < 16; ++j) xv[j] = x[(size_t)t * D_DIM + lane + 64 * j];
    double s[E_NUM];
#pragma unroll
    for (int e = 0; e < E_NUM; ++e) {
        const float* w = rw + e * D_DIM;
        double a = 0.0;
#pragma unroll
        for (int j = 0; j < 16; ++j) a += (double)xv[j] * (double)w[lane + 64 * j];
#pragma unroll
        for (int off = 32; off > 0; off >>= 1) a += __shfl_xor(a, off, 64);
        s[e] = a;
    }
    if (lane == 0) {
        int i0 = 0; double v0 = s[0];
#pragma unroll
        for (int e = 1; e < E_NUM; ++e) if (s[e] > v0) { v0 = s[e]; i0 = e; }
        int i1 = (i0 == 0) ? 1 : 0; double v1 = s[i1];
#pragma unroll
        for (int e = 0; e < E_NUM; ++e) if (e != i0 && e != i1 && s[e] > v1) { v1 = s[e]; i1 = e; }
        float e1 = expf((float)(v1 - v0));   // v1 <= v0
        float inv = 1.f / (1.f + e1);
        tok_e[t * 2 + 0] = i0; tok_w[t * 2 + 0] = inv;
        tok_e[t * 2 + 1] = i1; tok_w[t * 2 + 1] = e1 * inv;
        atomicAdd(&cnt[i0], 1);
        atomicAdd(&cnt[i1], 1);
    }
}

// ---------------- exclusive scan of 8 counts ----------------
__global__ void moe_scan(const int* __restrict__ cnt, int* __restrict__ offsets)
{
    if (threadIdx.x == 0) {
        int off = 0;
        for (int e = 0; e < E_NUM; ++e) { offsets[e] = off; off += cnt[e]; }
    }
}

// ---------------- place tokens into compact per-expert lists ----------------
__global__ __launch_bounds__(256) void moe_place(
    const int* __restrict__ tok_e, const float* __restrict__ tok_w,
    const int* __restrict__ offsets, int* __restrict__ pos,
    int* __restrict__ tok_list, float* __restrict__ wt_list,
    int* __restrict__ slot_pos)
{
    const int t = blockIdx.x * blockDim.x + threadIdx.x;
    if (t >= T_NUM) return;
#pragma unroll
    for (int k = 0; k < 2; ++k) {
        int e = tok_e[t * 2 + k];
        int p = atomicAdd(&pos[e], 1);
        int row = offsets[e] + p;
        if (row >= 2 * T_NUM) row = 2 * T_NUM - 1;
        tok_list[row] = t;
        wt_list[row] = tok_w[t * 2 + k];
        slot_pos[t * 2 + k] = row;
    }
}

// ---------------- GEMM1 (per expert e): h = gelu(x_g @ W1[e]^T) * w_tok ------
// grid (F/64, MAX_ROWS/16), block 256 (4 waves; wave = one 16x16 tile along N)
__global__ __launch_bounds__(256) void moe_gemm1(
    const float* __restrict__ x, const float* __restrict__ w1,
    const int* __restrict__ tok_list, const float* __restrict__ wt_list,
    const int* __restrict__ offsets, const int* __restrict__ cnt,
    bf16* __restrict__ h, int e)
{
    int M = cnt[e]; if (M > MAX_ROWS) M = MAX_ROWS;
    const int m0 = blockIdx.y * 16;
    if (m0 >= M) return;
    const int off_e = offsets[e];
    const int wave = threadIdx.x >> 6;
    const int lane = threadIdx.x & 63;
    const int quad = lane >> 4;
    const int l16 = lane & 15;
    const int n0 = blockIdx.x * 64 + wave * 16;

    const int arow = m0 + l16;
    int tok = tok_list[off_e + (arow < M ? arow : M - 1)];
    if ((unsigned)tok >= T_NUM) tok = 0;
    const float* aptr = x + (size_t)tok * D_DIM + quad * 8;
    const float* bptr = w1 + ((size_t)e * F_DIM + n0 + l16) * D_DIM + quad * 8;

    f32x4_t acc = {0.f, 0.f, 0.f, 0.f};
#pragma unroll 4
    for (int k0 = 0; k0 < D_DIM; k0 += 32) {
        bf16x8_t a = cvt8(aptr + k0);
        bf16x8_t b = cvt8(bptr + k0);
        acc = __builtin_amdgcn_mfma_f32_16x16x32_bf16(a, b, acc, 0, 0, 0);
    }
    const int col = n0 + l16;
#pragma unroll
    for (int reg = 0; reg < 4; ++reg) {
        const int r = m0 + quad * 4 + reg;   // C/D: col=lane&15, row=quad*4+reg
        if (r < M) {
            float wgt = wt_list[off_e + r];
            float v = acc[reg];
            float g = 0.5f * v * (1.0f + erff(v * 0.70710678118654752f));
            h[(size_t)r * F_DIM + col] = __float2bfloat16(g * wgt);
        }
    }
}

// ---------------- GEMM2 (per expert e): y[slot_row] = h @ W2[e]^T ------------
// grid (D/64, MAX_ROWS/16), block 256
__global__ __launch_bounds__(256) void moe_gemm2(
    const bf16* __restrict__ h, const float* __restrict__ w2,
    const int* __restrict__ offsets, const int* __restrict__ cnt,
    bf16* __restrict__ y, int e)
{
    int M = cnt[e]; if (M > MAX_ROWS) M = MAX_ROWS;
    const int m0 = blockIdx.y * 16;
    if (m0 >= M) return;
    const int off_e = offsets[e];
    const int wave = threadIdx.x >> 6;
    const int lane = threadIdx.x & 63;
    const int quad = lane >> 4;
    const int l16 = lane & 15;
    const int n0 = blockIdx.x * 64 + wave * 16;

    const int arow = m0 + l16;
    const int hrow = (arow < M ? arow : M - 1);
    const bf16* aptr = h + (size_t)hrow * F_DIM + quad * 8;
    const float* bptr = w2 + ((size_t)e * D_DIM + n0 + l16) * F_DIM + quad * 8;

    f32x4_t acc = {0.f, 0.f, 0.f, 0.f};
#pragma unroll 4
    for (int k0 = 0; k0 < F_DIM; k0 += 32) {
        bf16x8_t a = *(const bf16x8_t*)(aptr + k0);
        bf16x8_t b = cvt8(bptr + k0);
        acc = __builtin_amdgcn_mfma_f32_16x16x32_bf16(a, b, acc, 0, 0, 0);
    }
    const int col = n0 + l16;
#pragma unroll
    for (int reg = 0; reg < 4; ++reg) {
        const int r = m0 + quad * 4 + reg;
        if (r < M) {
            int yrow = off_e + r;
            if ((unsigned)yrow >= 2 * T_NUM) yrow = 0;
            y[(size_t)yrow * D_DIM + col] = __float2bfloat16(acc[reg]);
        }
    }
}

// ---------------- combine: out[t] = y[slot0(t)] + y[slot1(t)], FP32 OUT ------
__global__ __launch_bounds__(256) void moe_combine(
    const bf16* __restrict__ y, const int* __restrict__ slot_pos,
    float* __restrict__ out)
{
    const size_t i = ((size_t)blockIdx.x * blockDim.x + threadIdx.x) * 4;
    const int t = (int)(i >> 10);        // D_DIM = 1024
    const int d = (int)(i & (D_DIM - 1));
    int r0 = slot_pos[t * 2 + 0];
    int r1 = slot_pos[t * 2 + 1];
    if ((unsigned)r0 >= 2 * T_NUM) r0 = 0;
    if ((unsigned)r1 >= 2 * T_NUM) r1 = 0;
    bf16x4_t a = *(const bf16x4_t*)((const __bf16*)y + (size_t)r0 * D_DIM + d);
    bf16x4_t b = *(const bf16x4_t*)((const __bf16*)y + (size_t)r1 * D_DIM + d);
    float4 oo;
    oo.x = (float)a[0] + (float)b[0];
    oo.y = (float)a[1] + (float)b[1];
    oo.z = (float)a[2] + (float)b[2];
    oo.w = (float)a[3] + (float)b[3];
    *(float4*)(out + i) = oo;
}

extern "C" void kernel_launch(void* const* d_in, const int* in_sizes, int n_in,
                              void* d_out, int out_size, void* d_ws, size_t ws_size,
                              hipStream_t stream) {
    const float* x  = (const float*)d_in[0];
    const float* rw = (const float*)d_in[1];
    const float* w1 = (const float*)d_in[2];
    const float* w2 = (const float*)d_in[3];
    float* out = (float*)d_out;   // fp32 output per reference dtype

    char* ws = (char*)d_ws;
    size_t o = 0;
    int*   tok_e    = (int*)(ws + o);   o += (size_t)T_NUM * 2 * 4;
    float* tok_w    = (float*)(ws + o); o += (size_t)T_NUM * 2 * 4;
    int*   tok_list = (int*)(ws + o);   o += (size_t)2 * T_NUM * 4;
    float* wt_list  = (float*)(ws + o); o += (size_t)2 * T_NUM * 4;
    int*   slot_pos = (int*)(ws + o);   o += (size_t)2 * T_NUM * 4;
    int*   cnt      = (int*)(ws + o);   o += 32;
    int*   offsets  = (int*)(ws + o);   o += 32;
    int*   pos      = (int*)(ws + o);   o += 32;
    o = (o + 255) & ~(size_t)255;
    bf16*  y        = (bf16*)(ws + o);  o += (size_t)2 * T_NUM * D_DIM * 2;   // 32 MiB
    bf16*  h        = (bf16*)(ws + o);  o += (size_t)MAX_ROWS * F_DIM * 2;    // 32 MiB

    hipMemsetAsync(cnt, 0, 96, stream);

    moe_router<<<T_NUM, 64, 0, stream>>>(x, rw, cnt, tok_e, tok_w);
    moe_scan<<<1, 64, 0, stream>>>(cnt, offsets);
    moe_place<<<T_NUM / 256, 256, 0, stream>>>(tok_e, tok_w, offsets, pos,
                                               tok_list, wt_list, slot_pos);
    for (int e = 0; e < E_NUM; ++e) {
        moe_gemm1<<<dim3(F_DIM / 64, MAX_ROWS / 16), 256, 0, stream>>>(
            x, w1, tok_list, wt_list, offsets, cnt, h, e);
        moe_gemm2<<<dim3(D_DIM / 64, MAX_ROWS / 16), 256, 0, stream>>>(
            h, w2, offsets, cnt, y, e);
    }
    moe_combine<<<T_NUM * D_DIM / 1024, 256, 0, stream>>>(y, slot_pos, out);
}

// Round 6
// 1591.949 us; speedup vs baseline: 4.4103x; 4.4103x over previous
//
#include <hip/hip_runtime.h>
#include <hip/hip_bf16.h>
#include <math.h>

// MoE top-2, T=8192 tokens, D=1024, F=4096, E=8. Inputs fp32, output fp32.
// R6: m97-style 128x128x32 bf16 MFMA GEMMs with global_load_lds staging.
// Pre-pass converts w1/w2 to bf16 and gather-converts x rows to slot order.
// Falls back to the proven R5 path if ws_size < ~225 MiB.
//
// Fast ws: lists(~0.32 MiB) | y[16384x1024]bf16 | h[4096x4096]bf16 |
//          xg[16384x1024]bf16 | w1b[8x4096x1024]bf16 | w2b[8x1024x4096]bf16

#define D_DIM 1024
#define F_DIM 4096
#define E_NUM 8
#define T_NUM 8192
#define MAX_ROWS 4096
#define BM 128
#define BN 128
#define BK 32

typedef __bf16 bf16x8_t __attribute__((ext_vector_type(8)));
typedef __bf16 bf16x4_t __attribute__((ext_vector_type(4)));
typedef float f32x4_t __attribute__((ext_vector_type(4)));
using bf16 = __hip_bfloat16;

typedef __attribute__((address_space(1))) const void gvoid_t;
typedef __attribute__((address_space(3))) void svoid_t;

__device__ __forceinline__ void async16(void* lds, const void* g) {
    __builtin_amdgcn_global_load_lds((gvoid_t*)g, (svoid_t*)lds, 16, 0, 0);
}

__device__ __forceinline__ bf16x8_t cvt8(const float* __restrict__ p) {
    float4 f0 = *(const float4*)(p);
    float4 f1 = *(const float4*)(p + 4);
    bf16x8_t r;
    r[0] = (__bf16)f0.x; r[1] = (__bf16)f0.y; r[2] = (__bf16)f0.z; r[3] = (__bf16)f0.w;
    r[4] = (__bf16)f1.x; r[5] = (__bf16)f1.y; r[6] = (__bf16)f1.z; r[7] = (__bf16)f1.w;
    return r;
}

__device__ __forceinline__ float gelu(float v) {
    return 0.5f * v * (1.0f + erff(v * 0.70710678118654752f));
}

// ---------------- router: fp64-accum scores, top-2, softmax, counts ----------
__global__ __launch_bounds__(64) void moe_router(
    const float* __restrict__ x, const float* __restrict__ rw,
    int* __restrict__ cnt, int* __restrict__ tok_e, float* __restrict__ tok_w)
{
    const int t = blockIdx.x;
    const int lane = threadIdx.x;
    float xv[16];
#pragma unroll
    for (int j = 0; j < 16; ++j) xv[j] = x[(size_t)t * D_DIM + lane + 64 * j];
    double s[E_NUM];
#pragma unroll
    for (int e = 0; e < E_NUM; ++e) {
        const float* w = rw + e * D_DIM;
        double a = 0.0;
#pragma unroll
        for (int j = 0; j < 16; ++j) a += (double)xv[j] * (double)w[lane + 64 * j];
#pragma unroll
        for (int off = 32; off > 0; off >>= 1) a += __shfl_xor(a, off, 64);
        s[e] = a;
    }
    if (lane == 0) {
        int i0 = 0; double v0 = s[0];
#pragma unroll
        for (int e = 1; e < E_NUM; ++e) if (s[e] > v0) { v0 = s[e]; i0 = e; }
        int i1 = (i0 == 0) ? 1 : 0; double v1 = s[i1];
#pragma unroll
        for (int e = 0; e < E_NUM; ++e) if (e != i0 && e != i1 && s[e] > v1) { v1 = s[e]; i1 = e; }
        float e1 = expf((float)(v1 - v0));
        float inv = 1.f / (1.f + e1);
        tok_e[t * 2 + 0] = i0; tok_w[t * 2 + 0] = inv;
        tok_e[t * 2 + 1] = i1; tok_w[t * 2 + 1] = e1 * inv;
        atomicAdd(&cnt[i0], 1);
        atomicAdd(&cnt[i1], 1);
    }
}

__global__ void moe_scan(const int* __restrict__ cnt, int* __restrict__ offsets)
{
    if (threadIdx.x == 0) {
        int off = 0;
        for (int e = 0; e < E_NUM; ++e) { offsets[e] = off; off += cnt[e]; }
    }
}

__global__ __launch_bounds__(256) void moe_place(
    const int* __restrict__ tok_e, const float* __restrict__ tok_w,
    const int* __restrict__ offsets, int* __restrict__ pos,
    int* __restrict__ tok_list, float* __restrict__ wt_list,
    int* __restrict__ slot_pos)
{
    const int t = blockIdx.x * blockDim.x + threadIdx.x;
    if (t >= T_NUM) return;
#pragma unroll
    for (int k = 0; k < 2; ++k) {
        int e = tok_e[t * 2 + k];
        int p = atomicAdd(&pos[e], 1);
        int row = offsets[e] + p;
        if (row >= 2 * T_NUM) row = 2 * T_NUM - 1;
        tok_list[row] = t;
        wt_list[row] = tok_w[t * 2 + k];
        slot_pos[t * 2 + k] = row;
    }
}

// ---------------- prep: fp32 -> bf16 weight convert ----------------
__global__ __launch_bounds__(256) void cvt_f32_bf16(
    const float* __restrict__ src, __bf16* __restrict__ dst, int n)
{
    const int i = (blockIdx.x * 256 + threadIdx.x) * 4;
    if (i >= n) return;
    float4 v = *(const float4*)(src + i);
    bf16x4_t o;
    o[0] = (__bf16)v.x; o[1] = (__bf16)v.y; o[2] = (__bf16)v.z; o[3] = (__bf16)v.w;
    *(bf16x4_t*)(dst + i) = o;
}

// ---------------- prep: gather-convert x rows into slot order ----------------
__global__ __launch_bounds__(256) void moe_gather(
    const float* __restrict__ x, const int* __restrict__ tok_list,
    __bf16* __restrict__ xg)
{
    const int row = blockIdx.x;
    const int c = threadIdx.x * 4;
    int tok = tok_list[row];
    if ((unsigned)tok >= T_NUM) tok = 0;
    float4 v = *(const float4*)(x + (size_t)tok * D_DIM + c);
    bf16x4_t o;
    o[0] = (__bf16)v.x; o[1] = (__bf16)v.y; o[2] = (__bf16)v.z; o[3] = (__bf16)v.w;
    *(bf16x4_t*)(xg + (size_t)row * D_DIM + c) = o;
}

// ---------------- GEMM1 fast: h = gelu(xg_seg @ W1b[e]^T) * wt ---------------
// grid (F/128, MAX_ROWS/128), block 256. 128x128 tile, BK=32, m97 structure.
__global__ __launch_bounds__(256) void moe_gemm1_f(
    const __bf16* __restrict__ xg, const __bf16* __restrict__ w1b,
    const float* __restrict__ wt_list,
    const int* __restrict__ offsets, const int* __restrict__ cnt,
    __bf16* __restrict__ h, int e)
{
    int M = cnt[e]; if (M > MAX_ROWS) M = MAX_ROWS;
    const int m0 = blockIdx.y * BM;
    if (m0 >= M) return;
    const int off_e = offsets[e];
    const int n0 = blockIdx.x * BN;

    __shared__ __bf16 As[BM * BK];   // [row][k], 32 bf16 per row (64 B)
    __shared__ __bf16 Bs[BN * BK];

    const int tid = threadIdx.x;
    const int wave = tid >> 6;
    const int lane = tid & 63;
    const int quad = lane >> 4;
    const int l16 = lane & 15;
    const int wm = (wave >> 1) * 64;
    const int wn = (wave & 1) * 64;

    // staging: chunk c = i*256 + tid (i=0,1); row = c>>2, kchunk = c&3
    const int kc = (tid & 3) * 8;
    const int r0 = m0 + (tid >> 2);
    const int r1 = r0 + 64;
    const __bf16* a0 = xg + (size_t)(off_e + (r0 < M ? r0 : M - 1)) * D_DIM + kc;
    const __bf16* a1 = xg + (size_t)(off_e + (r1 < M ? r1 : M - 1)) * D_DIM + kc;
    const __bf16* b0 = w1b + ((size_t)e * F_DIM + n0 + (tid >> 2)) * D_DIM + kc;
    const __bf16* b1 = b0 + (size_t)64 * D_DIM;
    // wave-uniform LDS bases (HW adds lane*16 B)
    __bf16* asb0 = As + (size_t)(wave * 64) * 8;
    __bf16* asb1 = As + (size_t)(256 + wave * 64) * 8;
    __bf16* bsb0 = Bs + (size_t)(wave * 64) * 8;
    __bf16* bsb1 = Bs + (size_t)(256 + wave * 64) * 8;

    f32x4_t acc[4][4];
#pragma unroll
    for (int i = 0; i < 4; ++i)
#pragma unroll
        for (int j = 0; j < 4; ++j) acc[i][j] = (f32x4_t){0.f, 0.f, 0.f, 0.f};

    for (int k0 = 0; k0 < D_DIM; k0 += BK) {
        __syncthreads();
        async16(asb0, a0 + k0);
        async16(asb1, a1 + k0);
        async16(bsb0, b0 + k0);
        async16(bsb1, b1 + k0);
        __syncthreads();
        bf16x8_t af[4], bfr[4];
#pragma unroll
        for (int mi = 0; mi < 4; ++mi)
            af[mi] = *(const bf16x8_t*)&As[(wm + mi * 16 + l16) * BK + quad * 8];
#pragma unroll
        for (int ni = 0; ni < 4; ++ni)
            bfr[ni] = *(const bf16x8_t*)&Bs[(wn + ni * 16 + l16) * BK + quad * 8];
#pragma unroll
        for (int mi = 0; mi < 4; ++mi)
#pragma unroll
            for (int ni = 0; ni < 4; ++ni)
                acc[mi][ni] = __builtin_amdgcn_mfma_f32_16x16x32_bf16(
                    af[mi], bfr[ni], acc[mi][ni], 0, 0, 0);
    }

#pragma unroll
    for (int mi = 0; mi < 4; ++mi) {
#pragma unroll
        for (int reg = 0; reg < 4; ++reg) {
            const int r = m0 + wm + mi * 16 + quad * 4 + reg;
            if (r < M) {
                const float wgt = wt_list[off_e + r];
#pragma unroll
                for (int ni = 0; ni < 4; ++ni) {
                    const int col = n0 + wn + ni * 16 + l16;
                    h[(size_t)r * F_DIM + col] = (__bf16)(gelu(acc[mi][ni][reg]) * wgt);
                }
            }
        }
    }
}

// ---------------- GEMM2 fast: y[slot] = h_seg @ W2b[e]^T ---------------------
// grid (D/128, MAX_ROWS/128), block 256.
__global__ __launch_bounds__(256) void moe_gemm2_f(
    const __bf16* __restrict__ h, const __bf16* __restrict__ w2b,
    const int* __restrict__ offsets, const int* __restrict__ cnt,
    __bf16* __restrict__ y, int e)
{
    int M = cnt[e]; if (M > MAX_ROWS) M = MAX_ROWS;
    const int m0 = blockIdx.y * BM;
    if (m0 >= M) return;
    const int off_e = offsets[e];
    const int n0 = blockIdx.x * BN;

    __shared__ __bf16 As[BM * BK];
    __shared__ __bf16 Bs[BN * BK];

    const int tid = threadIdx.x;
    const int wave = tid >> 6;
    const int lane = tid & 63;
    const int quad = lane >> 4;
    const int l16 = lane & 15;
    const int wm = (wave >> 1) * 64;
    const int wn = (wave & 1) * 64;

    const int kc = (tid & 3) * 8;
    const int r0 = m0 + (tid >> 2);
    const int r1 = r0 + 64;
    const __bf16* a0 = h + (size_t)(r0 < M ? r0 : M - 1) * F_DIM + kc;
    const __bf16* a1 = h + (size_t)(r1 < M ? r1 : M - 1) * F_DIM + kc;
    const __bf16* b0 = w2b + ((size_t)e * D_DIM + n0 + (tid >> 2)) * F_DIM + kc;
    const __bf16* b1 = b0 + (size_t)64 * F_DIM;
    __bf16* asb0 = As + (size_t)(wave * 64) * 8;
    __bf16* asb1 = As + (size_t)(256 + wave * 64) * 8;
    __bf16* bsb0 = Bs + (size_t)(wave * 64) * 8;
    __bf16* bsb1 = Bs + (size_t)(256 + wave * 64) * 8;

    f32x4_t acc[4][4];
#pragma unroll
    for (int i = 0; i < 4; ++i)
#pragma unroll
        for (int j = 0; j < 4; ++j) acc[i][j] = (f32x4_t){0.f, 0.f, 0.f, 0.f};

    for (int k0 = 0; k0 < F_DIM; k0 += BK) {
        __syncthreads();
        async16(asb0, a0 + k0);
        async16(asb1, a1 + k0);
        async16(bsb0, b0 + k0);
        async16(bsb1, b1 + k0);
        __syncthreads();
        bf16x8_t af[4], bfr[4];
#pragma unroll
        for (int mi = 0; mi < 4; ++mi)
            af[mi] = *(const bf16x8_t*)&As[(wm + mi * 16 + l16) * BK + quad * 8];
#pragma unroll
        for (int ni = 0; ni < 4; ++ni)
            bfr[ni] = *(const bf16x8_t*)&Bs[(wn + ni * 16 + l16) * BK + quad * 8];
#pragma unroll
        for (int mi = 0; mi < 4; ++mi)
#pragma unroll
            for (int ni = 0; ni < 4; ++ni)
                acc[mi][ni] = __builtin_amdgcn_mfma_f32_16x16x32_bf16(
                    af[mi], bfr[ni], acc[mi][ni], 0, 0, 0);
    }

#pragma unroll
    for (int mi = 0; mi < 4; ++mi) {
#pragma unroll
        for (int reg = 0; reg < 4; ++reg) {
            const int r = m0 + wm + mi * 16 + quad * 4 + reg;
            if (r < M) {
#pragma unroll
                for (int ni = 0; ni < 4; ++ni) {
                    const int col = n0 + wn + ni * 16 + l16;
                    y[(size_t)(off_e + r) * D_DIM + col] = (__bf16)acc[mi][ni][reg];
                }
            }
        }
    }
}

// ---------------- combine: out[t] = y[slot0] + y[slot1], fp32 out ------------
__global__ __launch_bounds__(256) void moe_combine(
    const __bf16* __restrict__ y, const int* __restrict__ slot_pos,
    float* __restrict__ out)
{
    const size_t i = ((size_t)blockIdx.x * blockDim.x + threadIdx.x) * 4;
    const int t = (int)(i >> 10);
    const int d = (int)(i & (D_DIM - 1));
    int r0 = slot_pos[t * 2 + 0];
    int r1 = slot_pos[t * 2 + 1];
    if ((unsigned)r0 >= 2 * T_NUM) r0 = 0;
    if ((unsigned)r1 >= 2 * T_NUM) r1 = 0;
    bf16x4_t a = *(const bf16x4_t*)(y + (size_t)r0 * D_DIM + d);
    bf16x4_t b = *(const bf16x4_t*)(y + (size_t)r1 * D_DIM + d);
    float4 oo;
    oo.x = (float)a[0] + (float)b[0];
    oo.y = (float)a[1] + (float)b[1];
    oo.z = (float)a[2] + (float)b[2];
    oo.w = (float)a[3] + (float)b[3];
    *(float4*)(out + i) = oo;
}

// ================= fallback (R5, proven): 16x16 per-wave tiles ===============
__global__ __launch_bounds__(256) void moe_gemm1_s(
    const float* __restrict__ x, const float* __restrict__ w1,
    const int* __restrict__ tok_list, const float* __restrict__ wt_list,
    const int* __restrict__ offsets, const int* __restrict__ cnt,
    bf16* __restrict__ h, int e)
{
    int M = cnt[e]; if (M > MAX_ROWS) M = MAX_ROWS;
    const int m0 = blockIdx.y * 16;
    if (m0 >= M) return;
    const int off_e = offsets[e];
    const int wave = threadIdx.x >> 6;
    const int lane = threadIdx.x & 63;
    const int quad = lane >> 4;
    const int l16 = lane & 15;
    const int n0 = blockIdx.x * 64 + wave * 16;

    const int arow = m0 + l16;
    int tok = tok_list[off_e + (arow < M ? arow : M - 1)];
    if ((unsigned)tok >= T_NUM) tok = 0;
    const float* aptr = x + (size_t)tok * D_DIM + quad * 8;
    const float* bptr = w1 + ((size_t)e * F_DIM + n0 + l16) * D_DIM + quad * 8;

    f32x4_t acc = {0.f, 0.f, 0.f, 0.f};
#pragma unroll 4
    for (int k0 = 0; k0 < D_DIM; k0 += 32) {
        acc = __builtin_amdgcn_mfma_f32_16x16x32_bf16(cvt8(aptr + k0), cvt8(bptr + k0), acc, 0, 0, 0);
    }
    const int col = n0 + l16;
#pragma unroll
    for (int reg = 0; reg < 4; ++reg) {
        const int r = m0 + quad * 4 + reg;
        if (r < M) {
            float wgt = wt_list[off_e + r];
            h[(size_t)r * F_DIM + col] = __float2bfloat16(gelu(acc[reg]) * wgt);
        }
    }
}

__global__ __launch_bounds__(256) void moe_gemm2_s(
    const bf16* __restrict__ h, const float* __restrict__ w2,
    const int* __restrict__ offsets, const int* __restrict__ cnt,
    bf16* __restrict__ y, int e)
{
    int M = cnt[e]; if (M > MAX_ROWS) M = MAX_ROWS;
    const int m0 = blockIdx.y * 16;
    if (m0 >= M) return;
    const int off_e = offsets[e];
    const int wave = threadIdx.x >> 6;
    const int lane = threadIdx.x & 63;
    const int quad = lane >> 4;
    const int l16 = lane & 15;
    const int n0 = blockIdx.x * 64 + wave * 16;

    const int arow = m0 + l16;
    const int hrow = (arow < M ? arow : M - 1);
    const bf16* aptr = h + (size_t)hrow * F_DIM + quad * 8;
    const float* bptr = w2 + ((size_t)e * D_DIM + n0 + l16) * F_DIM + quad * 8;

    f32x4_t acc = {0.f, 0.f, 0.f, 0.f};
#pragma unroll 4
    for (int k0 = 0; k0 < F_DIM; k0 += 32) {
        acc = __builtin_amdgcn_mfma_f32_16x16x32_bf16(*(const bf16x8_t*)(aptr + k0), cvt8(bptr + k0), acc, 0, 0, 0);
    }
    const int col = n0 + l16;
#pragma unroll
    for (int reg = 0; reg < 4; ++reg) {
        const int r = m0 + quad * 4 + reg;
        if (r < M) {
            int yrow = off_e + r;
            if ((unsigned)yrow >= 2 * T_NUM) yrow = 0;
            y[(size_t)yrow * D_DIM + col] = __float2bfloat16(acc[reg]);
        }
    }
}

extern "C" void kernel_launch(void* const* d_in, const int* in_sizes, int n_in,
                              void* d_out, int out_size, void* d_ws, size_t ws_size,
                              hipStream_t stream) {
    const float* x  = (const float*)d_in[0];
    const float* rw = (const float*)d_in[1];
    const float* w1 = (const float*)d_in[2];
    const float* w2 = (const float*)d_in[3];
    float* out = (float*)d_out;

    char* ws = (char*)d_ws;
    size_t o = 0;
    int*   tok_e    = (int*)(ws + o);   o += (size_t)T_NUM * 2 * 4;
    float* tok_w    = (float*)(ws + o); o += (size_t)T_NUM * 2 * 4;
    int*   tok_list = (int*)(ws + o);   o += (size_t)2 * T_NUM * 4;
    float* wt_list  = (float*)(ws + o); o += (size_t)2 * T_NUM * 4;
    int*   slot_pos = (int*)(ws + o);   o += (size_t)2 * T_NUM * 4;
    int*   cnt      = (int*)(ws + o);   o += 32;
    int*   offsets  = (int*)(ws + o);   o += 32;
    int*   pos      = (int*)(ws + o);   o += 32;
    o = (o + 255) & ~(size_t)255;
    bf16*  y        = (bf16*)(ws + o);  o += (size_t)2 * T_NUM * D_DIM * 2;   // 32 MiB
    bf16*  h        = (bf16*)(ws + o);  o += (size_t)MAX_ROWS * F_DIM * 2;    // 32 MiB
    const size_t need_slow = o;
    __bf16* xg  = (__bf16*)(ws + o);    o += (size_t)2 * T_NUM * D_DIM * 2;   // 32 MiB
    __bf16* w1b = (__bf16*)(ws + o);    o += (size_t)E_NUM * F_DIM * D_DIM * 2; // 64 MiB
    __bf16* w2b = (__bf16*)(ws + o);    o += (size_t)E_NUM * D_DIM * F_DIM * 2; // 64 MiB
    const size_t need_fast = o;
    (void)need_slow;

    hipMemsetAsync(cnt, 0, 96, stream);

    moe_router<<<T_NUM, 64, 0, stream>>>(x, rw, cnt, tok_e, tok_w);
    moe_scan<<<1, 64, 0, stream>>>(cnt, offsets);
    moe_place<<<T_NUM / 256, 256, 0, stream>>>(tok_e, tok_w, offsets, pos,
                                               tok_list, wt_list, slot_pos);

    if (ws_size >= need_fast) {
        const int nw = E_NUM * F_DIM * D_DIM;  // 33.5M elems each
        cvt_f32_bf16<<<nw / 1024, 256, 0, stream>>>(w1, w1b, nw);
        cvt_f32_bf16<<<nw / 1024, 256, 0, stream>>>(w2, w2b, nw);
        moe_gather<<<2 * T_NUM, 256, 0, stream>>>(x, tok_list, xg);
        for (int e = 0; e < E_NUM; ++e) {
            moe_gemm1_f<<<dim3(F_DIM / BN, MAX_ROWS / BM), 256, 0, stream>>>(
                xg, w1b, wt_list, offsets, cnt, (__bf16*)h, e);
            moe_gemm2_f<<<dim3(D_DIM / BN, MAX_ROWS / BM), 256, 0, stream>>>(
                (const __bf16*)h, w2b, offsets, cnt, (__bf16*)y, e);
        }
    } else {
        for (int e = 0; e < E_NUM; ++e) {
            moe_gemm1_s<<<dim3(F_DIM / 64, MAX_ROWS / 16), 256, 0, stream>>>(
                x, w1, tok_list, wt_list, offsets, cnt, h, e);
            moe_gemm2_s<<<dim3(D_DIM / 64, MAX_ROWS / 16), 256, 0, stream>>>(
                h, w2, offsets, cnt, y, e);
        }
    }
    moe_combine<<<T_NUM * D_DIM / 1024, 256, 0, stream>>>((const __bf16*)y, slot_pos, out);
}